// Round 1
// baseline (202.003 us; speedup 1.0000x reference)
//
#include <hip/hip_runtime.h>
#include <hip/hip_fp16.h>

typedef _Float16 half2_t __attribute__((ext_vector_type(2)));
typedef _Float16 half4_t __attribute__((ext_vector_type(4)));
typedef _Float16 half8_t __attribute__((ext_vector_type(8)));
typedef float   float4_t __attribute__((ext_vector_type(4)));

static __device__ __forceinline__ half2_t cvt_pk(float a, float b) {
    return __builtin_bit_cast(half2_t, __builtin_amdgcn_cvt_pkrtz(a, b));
}
static __device__ __forceinline__ half4_t cvt_pk4(float a, float b, float c, float d) {
    half2_t lo = cvt_pk(a, b), hi = cvt_pk(c, d);
    half4_t r;
    r[0] = lo[0]; r[1] = lo[1]; r[2] = hi[0]; r[3] = hi[1];
    return r;
}
static __device__ __forceinline__ half8_t cvt_pk8(const float4& a, const float4& b) {
    half4_t lo = cvt_pk4(a.x, a.y, a.z, a.w);
    half4_t hi = cvt_pk4(b.x, b.y, b.z, b.w);
    return __builtin_shufflevector(lo, hi, 0, 1, 2, 3, 4, 5, 6, 7);
}

namespace {
constexpr int kB       = 16;    // batch
constexpr int kL       = 4096;  // Lq == Lk
constexpr int kD       = 64;    // head dim
constexpr int kQTile   = 128;   // 4 waves x 32 q-rows
constexpr int kBK      = 64;    // keys per tile
constexpr int kTiles   = kL / kBK;          // 64 key-tiles per batch
constexpr int kSplit   = 2;                 // K-split for occupancy (grid 512 -> 1024)
constexpr int kTilesHf = kTiles / kSplit;   // 32 key-tiles per half
constexpr int kTileH   = kBK * kD;          // 4096 halves per tile image
constexpr int kKStride = 72;    // Ksh stride (halves): kf b128 conflict-free, 16B-aligned
constexpr int kVStride = 68;    // Vsh stride (halves): vf b64 conflict-free (b64-only buffer)
constexpr size_t kWsHalves = (size_t)kB * kTiles * kTileH;  // 8 MB per operand
constexpr size_t kOHalves  = (size_t)kB * kL * kD;          // 8 MB fp16 partial O
}

// v12: K-split x2 (flash-decoding) on top of proven v11 inner loop.
// Rationale (rocprof): fa_fwd was grid-limited to 512 blocks = 2 blocks/CU =
// 2 waves/SIMD -> OccupancyPercent 19.4, MfmaUtil 38, VALUBusy 38, HBM 8.8%.
// Latency-bound, not pipe-bound: barriers + softmax shfl/exp2 chains can't be
// hidden by 2 waves/SIMD. Split keys 0..2047 / 2048..4095 across blockIdx.z:
// grid 1024 = 4 blocks/CU = 4 waves/SIMD. Inner loop is byte-identical to v11
// (strides 72/68, register prefetch, ones-column-MFMA l, -32 C-init).
// Half 0 -> Out (fp32, normalized) + (m,l); half 1 -> ws fp16 + (m,l);
// combine kernel merges with w_i = l_i * 2^(m_i - m) (the -32 shift cancels).
// ws: 16.8 (KV images) + 8.4 (O2 fp16) + 1.05 (ml) = 26.2 MB < 34 MB proven.

__global__ __launch_bounds__(256) void prep_kv(const float* __restrict__ K,
                                               const float* __restrict__ V,
                                               _Float16* __restrict__ Kws,
                                               _Float16* __restrict__ Vws)
{
    int blk = blockIdx.x;
    const int tid = threadIdx.x;
    if (blk < kB * kTiles) {
        // K image: plain fp16 row-major per tile (half-index task*8, task=r*8+g)
        const float* src = K + (size_t)blk * kTileH;
        _Float16* dst = Kws + (size_t)blk * kTileH;
#pragma unroll
        for (int i = 0; i < 2; ++i) {
            const int task = tid + 256 * i;
            const float* p = src + task * 8;
            const float4 a  = *(const float4*)p;
            const float4 b2 = *(const float4*)(p + 4);
            *(half8_t*)(dst + task * 8) = cvt_pk8(a, b2);
        }
    } else {
        // V^T image: [c8 chunk][d][8 keys] halves; reads coalesced across d
        blk -= kB * kTiles;
        const float* src = V + (size_t)blk * kTileH;   // [key][d]
        _Float16* dst = Vws + (size_t)blk * kTileH;
        const int d  = tid & 63;
        const int vw = tid >> 6;
#pragma unroll
        for (int i = 0; i < 2; ++i) {
            const int c8 = vw * 2 + i;
            const int k0 = c8 * 8;
            float p[8];
#pragma unroll
            for (int j = 0; j < 8; ++j) p[j] = src[(k0 + j) * kD + d];
            half4_t lo = cvt_pk4(p[0], p[1], p[2], p[3]);
            half4_t hi = cvt_pk4(p[4], p[5], p[6], p[7]);
            *(half8_t*)(dst + (c8 * 64 + d) * 8) =
                __builtin_shufflevector(lo, hi, 0, 1, 2, 3, 4, 5, 6, 7);
        }
    }
}

__global__ __launch_bounds__(256, 2)
void fa_fwd(const float* __restrict__ Q, const _Float16* __restrict__ Kws,
            const _Float16* __restrict__ Vws, const float* __restrict__ scale_ptr,
            float* __restrict__ Out, _Float16* __restrict__ O2ws,
            float* __restrict__ Mlws)
{
    __shared__ __align__(16) _Float16 Ksh[kBK * kKStride];  // Ksh[key][d]
    __shared__ __align__(16) _Float16 Vsh[kD * kVStride];   // Vsh[d][key] (transposed)

    const int tid  = threadIdx.x;
    const int wave = tid >> 6;
    const int lane = tid & 63;
    const int c    = lane & 15;   // intra-16 index (q-col in S^T, d-col in O)
    const int qd   = lane >> 4;   // quad 0..3

    const int b  = blockIdx.y;
    const int hf = blockIdx.z;    // key-split half
    const int q0 = blockIdx.x * kQTile + wave * 32;

    // staging decompositions (match image layouts)
    const int task0 = tid, task1 = tid + 256;          // K: r=task>>3, g=task&7
    const int vd = tid & 63;                           // V: this thread's d
    const int vw = tid >> 6;                           // V: chunk pair base

    const float qscale = 1.4426950408889634f / scale_ptr[0];

    const float*    Qb = Q   + (size_t)b * kL * kD;
    const _Float16* Kt = Kws + ((size_t)b * kTiles + (size_t)hf * kTilesHf) * kTileH;
    const _Float16* Vt = Vws + ((size_t)b * kTiles + (size_t)hf * kTilesHf) * kTileH;

    // ---- Q fragments (B-operand of 16x16x32: n=lane&15=qrow, k=8*quad+j=d) ----
    half8_t qfrag[2][2];
#pragma unroll
    for (int qt = 0; qt < 2; ++qt) {
        const float* qrow = Qb + (size_t)(q0 + qt * 16 + c) * kD;
#pragma unroll
        for (int dk = 0; dk < 2; ++dk) {
            const float* p = qrow + dk * 32 + qd * 8;
            half8_t h;
#pragma unroll
            for (int j = 0; j < 8; ++j) h[j] = (_Float16)(p[j] * qscale);
            qfrag[qt][dk] = h;
        }
    }

    float4_t O[2][4];
    float4_t O5[2];   // l accumulator via ones-column MFMA (O-row layout)
#pragma unroll
    for (int qt = 0; qt < 2; ++qt) {
        O5[qt] = (float4_t)0.0f;
#pragma unroll
        for (int dt = 0; dt < 4; ++dt) O[qt][dt] = (float4_t)0.0f;
    }
    float m_run[2] = {-__builtin_inff(), -__builtin_inff()};

    const half4_t vone = {(_Float16)1.0f, (_Float16)1.0f, (_Float16)1.0f, (_Float16)1.0f};

    // ---- prefetch tile 0 (4x half8 = 16 VGPRs) ----
    half8_t kp[2], vp[2];
    kp[0] = *(const half8_t*)(Kt + task0 * 8);
    kp[1] = *(const half8_t*)(Kt + task1 * 8);
    vp[0] = *(const half8_t*)(Vt + ((vw * 2 + 0) * 64 + vd) * 8);
    vp[1] = *(const half8_t*)(Vt + ((vw * 2 + 1) * 64 + vd) * 8);

    for (int t = 0; t < kTilesHf; ++t) {
        __syncthreads();  // previous tile's LDS readers done

        // ---- commit K (2x b128) ----
        *(half8_t*)(&Ksh[(task0 >> 3) * kKStride + (task0 & 7) * 8]) = kp[0];
        *(half8_t*)(&Ksh[(task1 >> 3) * kKStride + (task1 & 7) * 8]) = kp[1];
        // ---- commit V (4x b64; Vsh stride 68 is only 8B-aligned) ----
#pragma unroll
        for (int i = 0; i < 2; ++i) {
            const int c8 = vw * 2 + i;
            *(half4_t*)(&Vsh[vd * kVStride + c8 * 8])     =
                __builtin_shufflevector(vp[i], vp[i], 0, 1, 2, 3);
            *(half4_t*)(&Vsh[vd * kVStride + c8 * 8 + 4]) =
                __builtin_shufflevector(vp[i], vp[i], 4, 5, 6, 7);
        }
        __syncthreads();

        // ---- prefetch NEXT tile (wraps to tile 0 on last iter, unused) ----
        {
            const int nt = (t + 1) & (kTilesHf - 1);
            const _Float16* kn = Kt + (size_t)nt * kTileH;
            const _Float16* vn = Vt + (size_t)nt * kTileH;
            kp[0] = *(const half8_t*)(kn + task0 * 8);
            kp[1] = *(const half8_t*)(kn + task1 * 8);
            vp[0] = *(const half8_t*)(vn + ((vw * 2 + 0) * 64 + vd) * 8);
            vp[1] = *(const half8_t*)(vn + ((vw * 2 + 1) * 64 + vd) * 8);
        }

        // ---- K fragments (A-operand: m=lane&15=key, k=8*quad+j=d) ----
        half8_t kf[4][2];
#pragma unroll
        for (int kt = 0; kt < 4; ++kt)
#pragma unroll
            for (int dk = 0; dk < 2; ++dk)
                kf[kt][dk] = *(const half8_t*)(&Ksh[(kt * 16 + c) * kKStride + dk * 32 + qd * 8]);

        // ---- S^T = K * Q^T  (C-init = -32: free shift, fp16 overflow margin) ----
        float4_t S[4][2];
#pragma unroll
        for (int kt = 0; kt < 4; ++kt)
#pragma unroll
            for (int qt = 0; qt < 2; ++qt) {
                float4_t acc = {-32.0f, -32.0f, -32.0f, -32.0f};
                acc = __builtin_amdgcn_mfma_f32_16x16x32_f16(kf[kt][0], qfrag[qt][0], acc, 0, 0, 0);
                acc = __builtin_amdgcn_mfma_f32_16x16x32_f16(kf[kt][1], qfrag[qt][1], acc, 0, 0, 0);
                S[kt][qt] = acc;
            }

        // ---- online softmax per q-tile (S^T layout: lane column = q-row = c) ----
        half4_t pf[4][2];
#pragma unroll
        for (int qt = 0; qt < 2; ++qt) {
            float tm = S[0][qt][0];
#pragma unroll
            for (int kt = 0; kt < 4; ++kt)
#pragma unroll
                for (int r = 0; r < 4; ++r) tm = fmaxf(tm, S[kt][qt][r]);
            tm = fmaxf(tm, __shfl_xor(tm, 16));
            tm = fmaxf(tm, __shfl_xor(tm, 32));

            const bool newmax = tm > m_run[qt];
            const float mn = newmax ? tm : m_run[qt];
            if (__ballot(newmax)) {  // wave-uniform: skip when no row max moved
                const float alpha = __builtin_amdgcn_exp2f(m_run[qt] - mn);  // 1st iter: 0
                m_run[qt] = mn;
#pragma unroll
                for (int r = 0; r < 4; ++r) {
                    const float a = __shfl(alpha, qd * 4 + r);
#pragma unroll
                    for (int dt = 0; dt < 4; ++dt) O[qt][dt][r] *= a;
                    O5[qt][r] *= a;
                }
            }

            // P = exp2(S - m), pack to fp16 A-fragments (l comes from ones-MFMA)
#pragma unroll
            for (int kt = 0; kt < 4; ++kt) {
                const float p0 = __builtin_amdgcn_exp2f(S[kt][qt][0] - mn);
                const float p1 = __builtin_amdgcn_exp2f(S[kt][qt][1] - mn);
                const float p2 = __builtin_amdgcn_exp2f(S[kt][qt][2] - mn);
                const float p3 = __builtin_amdgcn_exp2f(S[kt][qt][3] - mn);
                pf[kt][qt] = cvt_pk4(p0, p1, p2, p3);
            }
        }

        // ---- O += P*V ; l += P*1  (vf b64 conflict-free, shared across q-tiles) ----
#pragma unroll
        for (int kt = 0; kt < 4; ++kt) {
#pragma unroll
            for (int dt = 0; dt < 4; ++dt) {
                const half4_t vf = *(const half4_t*)(
                    &Vsh[(dt * 16 + c) * kVStride + kt * 16 + qd * 4]);
#pragma unroll
                for (int qt = 0; qt < 2; ++qt)
                    O[qt][dt] = __builtin_amdgcn_mfma_f32_16x16x16f16(pf[kt][qt], vf, O[qt][dt], 0, 0, 0);
            }
#pragma unroll
            for (int qt = 0; qt < 2; ++qt)
                O5[qt] = __builtin_amdgcn_mfma_f32_16x16x16f16(pf[kt][qt], vone, O5[qt], 0, 0, 0);
        }
    }

    // ---- epilogue: l already in O-row layout; m fetched per-row via shfl ----
#pragma unroll
    for (int qt = 0; qt < 2; ++qt)
#pragma unroll
        for (int r = 0; r < 4; ++r) {
            const float l   = O5[qt][r];
            const float inv = 1.0f / l;
            // row max for q-row (qd*4+r): lives in lane c == qd*4+r (any quad)
            const float mrow = __shfl(m_run[qt], qd * 4 + r);
            const int qrow  = q0 + qt * 16 + qd * 4 + r;
            if (hf == 0) {
                float* op = Out + ((size_t)b * kL + qrow) * kD;
#pragma unroll
                for (int dt = 0; dt < 4; ++dt)
                    op[dt * 16 + c] = O[qt][dt][r] * inv;
            } else {
                _Float16* op = O2ws + ((size_t)b * kL + qrow) * kD;
#pragma unroll
                for (int dt = 0; dt < 4; ++dt)
                    op[dt * 16 + c] = (_Float16)(O[qt][dt][r] * inv);
            }
            if (c == 0) {
                float* mp = Mlws + (((size_t)b * kL + qrow) * 2 + hf) * 2;
                mp[0] = mrow;
                mp[1] = l;
            }
        }
}

// Merge the two key-halves: Out = w1*O1 + w2*O2, w_i = l_i*2^(m_i-m) / sum.
__global__ __launch_bounds__(256)
void combine(float* __restrict__ Out, const _Float16* __restrict__ O2ws,
             const float* __restrict__ Mlws)
{
    const int t   = threadIdx.x;
    const int row = blockIdx.x * 16 + (t >> 4);   // global row in [0, kB*kL)
    const int d0  = (t & 15) * 4;

    const float m1 = Mlws[(size_t)row * 4 + 0];
    const float l1 = Mlws[(size_t)row * 4 + 1];
    const float m2 = Mlws[(size_t)row * 4 + 2];
    const float l2 = Mlws[(size_t)row * 4 + 3];

    const float m  = fmaxf(m1, m2);
    float w1 = l1 * exp2f(m1 - m);
    float w2 = l2 * exp2f(m2 - m);
    const float inv = 1.0f / (w1 + w2);
    w1 *= inv; w2 *= inv;

    float* op = Out + (size_t)row * kD + d0;
    const _Float16* o2 = O2ws + (size_t)row * kD + d0;
    float4 a = *(const float4*)op;
    const half4_t h = *(const half4_t*)o2;
    a.x = a.x * w1 + (float)h[0] * w2;
    a.y = a.y * w1 + (float)h[1] * w2;
    a.z = a.z * w1 + (float)h[2] * w2;
    a.w = a.w * w1 + (float)h[3] * w2;
    *(float4*)op = a;
}

extern "C" void kernel_launch(void* const* d_in, const int* in_sizes, int n_in,
                              void* d_out, int out_size, void* d_ws, size_t ws_size,
                              hipStream_t stream) {
    const float* Q = (const float*)d_in[0];
    const float* K = (const float*)d_in[1];
    const float* V = (const float*)d_in[2];
    const float* s = (const float*)d_in[3];
    float* out = (float*)d_out;
    _Float16* Kws  = (_Float16*)d_ws;
    _Float16* Vws  = Kws + kWsHalves;
    _Float16* O2ws = Vws + kWsHalves;                 // 8.4 MB fp16 partial (half 1)
    float*    Mlws = (float*)(O2ws + kOHalves);       // [b*L][half][{m,l}] = 1.05 MB
    // total ws use: 16.8 + 8.4 + 1.05 = 26.2 MB  (>=34 MB proven in R5)

    prep_kv<<<dim3(2 * kB * kTiles), dim3(256), 0, stream>>>(K, V, Kws, Vws);
    fa_fwd<<<dim3(kL / kQTile, kB, kSplit), dim3(256), 0, stream>>>(Q, Kws, Vws, s, out, O2ws, Mlws);
    combine<<<dim3(kB * kL / 16), dim3(256), 0, stream>>>(out, O2ws, Mlws);
}

// Round 2
// 188.492 us; speedup vs baseline: 1.0717x; 1.0717x over previous
//
#include <hip/hip_runtime.h>
#include <hip/hip_fp16.h>

typedef _Float16 half2_t __attribute__((ext_vector_type(2)));
typedef _Float16 half4_t __attribute__((ext_vector_type(4)));
typedef _Float16 half8_t __attribute__((ext_vector_type(8)));
typedef float   float4_t __attribute__((ext_vector_type(4)));
typedef float  float16_t __attribute__((ext_vector_type(16)));

static __device__ __forceinline__ half2_t cvt_pk(float a, float b) {
    return __builtin_bit_cast(half2_t, __builtin_amdgcn_cvt_pkrtz(a, b));
}
static __device__ __forceinline__ half4_t cvt_pk4(float a, float b, float c, float d) {
    half2_t lo = cvt_pk(a, b), hi = cvt_pk(c, d);
    half4_t r;
    r[0] = lo[0]; r[1] = lo[1]; r[2] = hi[0]; r[3] = hi[1];
    return r;
}
static __device__ __forceinline__ half8_t cvt_pk8(const float4& a, const float4& b) {
    half4_t lo = cvt_pk4(a.x, a.y, a.z, a.w);
    half4_t hi = cvt_pk4(b.x, b.y, b.z, b.w);
    return __builtin_shufflevector(lo, hi, 0, 1, 2, 3, 4, 5, 6, 7);
}
static __device__ __forceinline__ half8_t join8(half4_t lo, half4_t hi) {
    return __builtin_shufflevector(lo, hi, 0, 1, 2, 3, 4, 5, 6, 7);
}

namespace {
constexpr int kB       = 16;    // batch
constexpr int kL       = 4096;  // Lq == Lk
constexpr int kD       = 64;    // head dim
constexpr int kQTile   = 128;   // 4 waves x 32 q-rows
constexpr int kBK      = 64;    // keys per tile
constexpr int kTiles   = kL / kBK;          // 64 key-tiles per batch
constexpr int kSplit   = 2;                 // K-split (grid 1024)
constexpr int kTilesHf = kTiles / kSplit;   // 32 key-tiles per half
constexpr int kTileH   = kBK * kD;          // 4096 halves per tile image
constexpr int kKStride = 72;    // Ksh stride (halves): b128 reads, even bank groups
constexpr int kVStride = 72;    // Vsh stride (halves): b128 reads/writes now
constexpr size_t kWsHalves = (size_t)kB * kTiles * kTileH;  // 8 MB per operand
constexpr size_t kOHalves  = (size_t)kB * kL * kD;          // 8 MB fp16 partial O
}

// v13: 32x32x16 restructure. R1 evidence: occupancy bump gave only -6.5% ->
// per-wave serial softmax chain (2x shfl_xor + 8x ds_bpermute broadcasts per
// tile) + half-rate 16x16x16 PV are the limiters, not wave count.
// New structure per wave (32 q-rows x 64-key tile):
//  - QK: 8x mfma_f32_32x32x16_f16 (2 key-blocks x 4 d-chunks). S^T layout:
//    col=lane&31=q (m74/m101-verified) -> each lane holds 16 scores of ITS OWN
//    q-row; the lane^32 partner holds the other 16.
//  - softmax: local fmax tree + ONE shfl_xor(32); m/alpha/l all lane-local
//    (no ballot-broadcasts, no per-row shuffles). T13 defer-max THR=8.
//  - PV: 8x full-rate 32x32x16 (A=V^T from LDS, B=P packed in-reg). The
//    S-reg -> B-operand key order is fixed by permuting K-image rows with
//    key' = key with bits 2<->3 swapped (bijective, zero runtime cost):
//    reg r,hi then holds logical key 16*(r>>3)+8*hi+4*((r>>2)&1)+(r&3), so
//    pf[kb] = pack(e[8kb..8kb+7]) matches B k=hi*8+j exactly. V natural order.
//  - l via local f32 tree + shfl_xor(32) (ones-MFMA removed).
// LDS: both strides 72 -> all commits/reads b128, even bank-group spread
// (8 lanes/group = minimum LDS cycles, no conflict penalty).

__global__ __launch_bounds__(256) void prep_kv(const float* __restrict__ K,
                                               const float* __restrict__ V,
                                               _Float16* __restrict__ Kws,
                                               _Float16* __restrict__ Vws)
{
    int blk = blockIdx.x;
    const int tid = threadIdx.x;
    if (blk < kB * kTiles) {
        // K image: fp16 row-major per tile, with key bits 2<->3 swapped so the
        // 32x32 MFMA S-reg order matches the PV B-operand key order.
        const float* src = K + (size_t)blk * kTileH;
        _Float16* dst = Kws + (size_t)blk * kTileH;
#pragma unroll
        for (int i = 0; i < 2; ++i) {
            const int task = tid + 256 * i;
            const int row  = task >> 3;       // dst physical row 0..63
            const int g    = task & 7;
            const int srow = (row & ~12) | ((row & 4) << 1) | ((row & 8) >> 1);
            const float* p = src + srow * kD + g * 8;
            const float4 a  = *(const float4*)p;
            const float4 b2 = *(const float4*)(p + 4);
            *(half8_t*)(dst + task * 8) = cvt_pk8(a, b2);
        }
    } else {
        // V^T image: [c8 chunk][d][8 keys] halves; natural key order
        blk -= kB * kTiles;
        const float* src = V + (size_t)blk * kTileH;   // [key][d]
        _Float16* dst = Vws + (size_t)blk * kTileH;
        const int d  = tid & 63;
        const int vw = tid >> 6;
#pragma unroll
        for (int i = 0; i < 2; ++i) {
            const int c8 = vw * 2 + i;
            const int k0 = c8 * 8;
            float p[8];
#pragma unroll
            for (int j = 0; j < 8; ++j) p[j] = src[(k0 + j) * kD + d];
            half4_t lo = cvt_pk4(p[0], p[1], p[2], p[3]);
            half4_t hi = cvt_pk4(p[4], p[5], p[6], p[7]);
            *(half8_t*)(dst + (c8 * 64 + d) * 8) = join8(lo, hi);
        }
    }
}

__global__ __launch_bounds__(256, 3)
void fa_fwd(const float* __restrict__ Q, const _Float16* __restrict__ Kws,
            const _Float16* __restrict__ Vws, const float* __restrict__ scale_ptr,
            float* __restrict__ Out, _Float16* __restrict__ O2ws,
            float* __restrict__ Mlws)
{
    __shared__ __align__(16) _Float16 Ksh[kBK * kKStride];  // Ksh[key_phys][d]
    __shared__ __align__(16) _Float16 Vsh[kD * kVStride];   // Vsh[d][key] (V^T)

    const int tid  = threadIdx.x;
    const int wave = tid >> 6;
    const int lane = tid & 63;
    const int l31  = lane & 31;   // q-row (QK B / PV B col); key row (QK A); d row (PV A)
    const int hi   = lane >> 5;   // half-select: k = hi*8 + j

    const int b  = blockIdx.y;
    const int hf = blockIdx.z;    // key-split half
    const int q0 = blockIdx.x * kQTile + wave * 32;

    // staging decompositions (match image layouts)
    const int task0 = tid, task1 = tid + 256;          // K: row=task>>3, g=task&7
    const int vd = tid & 63;                           // V: this thread's d
    const int vw = tid >> 6;                           // V: chunk pair base

    const float qscale = 1.4426950408889634f / scale_ptr[0];

    const float*    Qb = Q   + (size_t)b * kL * kD;
    const _Float16* Kt = Kws + ((size_t)b * kTiles + (size_t)hf * kTilesHf) * kTileH;
    const _Float16* Vt = Vws + ((size_t)b * kTiles + (size_t)hf * kTilesHf) * kTileH;

    // ---- Q fragments (B-operand 32x32x16: n=l31=qrow, k=hi*8+j, d=kd*16+k) ----
    half8_t qfrag[4];
    {
        const float* qrow = Qb + (size_t)(q0 + l31) * kD;
#pragma unroll
        for (int kd = 0; kd < 4; ++kd) {
            const float* p = qrow + kd * 16 + hi * 8;
            half8_t h;
#pragma unroll
            for (int j = 0; j < 8; ++j) h[j] = (_Float16)(p[j] * qscale);
            qfrag[kd] = h;
        }
    }

    // O^T accumulators: col=l31=q, row=d=(r&3)+8*(r>>2)+4*hi (+32*dt)
    float16_t O[2];
    O[0] = (float16_t)0.0f;
    O[1] = (float16_t)0.0f;
    float m_run = -__builtin_inff();
    float l_run = 0.0f;
    const float16_t Zc = (float16_t)0.0f;

    // ---- prefetch tile 0 (4x half8 = 16 VGPRs) ----
    half8_t kp[2], vp[2];
    kp[0] = *(const half8_t*)(Kt + task0 * 8);
    kp[1] = *(const half8_t*)(Kt + task1 * 8);
    vp[0] = *(const half8_t*)(Vt + ((vw * 2 + 0) * 64 + vd) * 8);
    vp[1] = *(const half8_t*)(Vt + ((vw * 2 + 1) * 64 + vd) * 8);

    for (int t = 0; t < kTilesHf; ++t) {
        __syncthreads();  // previous tile's LDS readers done

        // ---- commit K (2x b128) ----
        *(half8_t*)(&Ksh[(task0 >> 3) * kKStride + (task0 & 7) * 8]) = kp[0];
        *(half8_t*)(&Ksh[(task1 >> 3) * kKStride + (task1 & 7) * 8]) = kp[1];
        // ---- commit V (2x b128; stride 72 = 16B-aligned rows) ----
        *(half8_t*)(&Vsh[vd * kVStride + (vw * 2 + 0) * 8]) = vp[0];
        *(half8_t*)(&Vsh[vd * kVStride + (vw * 2 + 1) * 8]) = vp[1];
        __syncthreads();

        // ---- prefetch NEXT tile ----
        {
            const int nt = (t + 1) & (kTilesHf - 1);
            const _Float16* kn = Kt + (size_t)nt * kTileH;
            const _Float16* vn = Vt + (size_t)nt * kTileH;
            kp[0] = *(const half8_t*)(kn + task0 * 8);
            kp[1] = *(const half8_t*)(kn + task1 * 8);
            vp[0] = *(const half8_t*)(vn + ((vw * 2 + 0) * 64 + vd) * 8);
            vp[1] = *(const half8_t*)(vn + ((vw * 2 + 1) * 64 + vd) * 8);
        }

        // ---- S^T = K_phys * Q^T : 2 key-blocks x 4 d-chunks of 32x32x16 ----
        float16_t S0, S1;
        {
            half8_t kf0, kf1;
            kf0 = *(const half8_t*)(&Ksh[(l31)      * kKStride + 0 * 16 + hi * 8]);
            kf1 = *(const half8_t*)(&Ksh[(32 + l31) * kKStride + 0 * 16 + hi * 8]);
            S0 = __builtin_amdgcn_mfma_f32_32x32x16_f16(kf0, qfrag[0], Zc, 0, 0, 0);
            S1 = __builtin_amdgcn_mfma_f32_32x32x16_f16(kf1, qfrag[0], Zc, 0, 0, 0);
#pragma unroll
            for (int kd = 1; kd < 4; ++kd) {
                kf0 = *(const half8_t*)(&Ksh[(l31)      * kKStride + kd * 16 + hi * 8]);
                kf1 = *(const half8_t*)(&Ksh[(32 + l31) * kKStride + kd * 16 + hi * 8]);
                S0 = __builtin_amdgcn_mfma_f32_32x32x16_f16(kf0, qfrag[kd], S0, 0, 0, 0);
                S1 = __builtin_amdgcn_mfma_f32_32x32x16_f16(kf1, qfrag[kd], S1, 0, 0, 0);
            }
        }

        // ---- online softmax: everything lane-local except ONE shfl_xor(32) ----
#define M4(v,a) fmaxf(fmaxf(v[a], v[(a)+1]), fmaxf(v[(a)+2], v[(a)+3]))
        float pm = fmaxf(
            fmaxf(fmaxf(M4(S0, 0), M4(S0, 4)), fmaxf(M4(S0, 8), M4(S0, 12))),
            fmaxf(fmaxf(M4(S1, 0), M4(S1, 4)), fmaxf(M4(S1, 8), M4(S1, 12))));
#undef M4
        pm = fmaxf(pm, __shfl_xor(pm, 32));

        // T13 defer-max: skip rescale while growth <= 8 (P bounded by 2^8, exact)
        const bool need = pm > m_run + 8.0f;
        if (__ballot(need)) {
            const float mn    = fmaxf(m_run, pm);
            const float alpha = __builtin_amdgcn_exp2f(m_run - mn);  // 1st iter: 0
            m_run = mn;
            l_run *= alpha;
#pragma unroll
            for (int r = 0; r < 16; ++r) { O[0][r] *= alpha; O[1][r] *= alpha; }
        }

        // ---- P = exp2(S - m) in place; pack B-fragments; local l sum ----
#pragma unroll
        for (int r = 0; r < 16; ++r) {
            S0[r] = __builtin_amdgcn_exp2f(S0[r] - m_run);
            S1[r] = __builtin_amdgcn_exp2f(S1[r] - m_run);
        }
        half8_t pf[4];
        pf[0] = join8(cvt_pk4(S0[0],  S0[1],  S0[2],  S0[3]),
                      cvt_pk4(S0[4],  S0[5],  S0[6],  S0[7]));
        pf[1] = join8(cvt_pk4(S0[8],  S0[9],  S0[10], S0[11]),
                      cvt_pk4(S0[12], S0[13], S0[14], S0[15]));
        pf[2] = join8(cvt_pk4(S1[0],  S1[1],  S1[2],  S1[3]),
                      cvt_pk4(S1[4],  S1[5],  S1[6],  S1[7]));
        pf[3] = join8(cvt_pk4(S1[8],  S1[9],  S1[10], S1[11]),
                      cvt_pk4(S1[12], S1[13], S1[14], S1[15]));
#define A4(v,a) ((v[a] + v[(a)+1]) + (v[(a)+2] + v[(a)+3]))
        float lt = ((A4(S0, 0) + A4(S0, 4)) + (A4(S0, 8) + A4(S0, 12)))
                 + ((A4(S1, 0) + A4(S1, 4)) + (A4(S1, 8) + A4(S1, 12)));
#undef A4
        lt += __shfl_xor(lt, 32);
        l_run += lt;

        // ---- O^T += V^T * P : 4 key16-blocks x 2 d-blocks, full-rate x32x16 ----
#pragma unroll
        for (int kb = 0; kb < 4; ++kb) {
            const half8_t vf0 = *(const half8_t*)(
                &Vsh[(l31)      * kVStride + kb * 16 + hi * 8]);
            const half8_t vf1 = *(const half8_t*)(
                &Vsh[(32 + l31) * kVStride + kb * 16 + hi * 8]);
            O[0] = __builtin_amdgcn_mfma_f32_32x32x16_f16(vf0, pf[kb], O[0], 0, 0, 0);
            O[1] = __builtin_amdgcn_mfma_f32_32x32x16_f16(vf1, pf[kb], O[1], 0, 0, 0);
        }
    }

    // ---- epilogue: lane-local l, m; O^T reg r -> d = (r&3)+8*(r>>2)+4*hi+32*dt ----
    const float inv = 1.0f / l_run;
    const int   q   = q0 + l31;
    if (hf == 0) {
        float* op = Out + ((size_t)b * kL + q) * kD;
#pragma unroll
        for (int dt = 0; dt < 2; ++dt)
#pragma unroll
            for (int rr = 0; rr < 4; ++rr) {
                const int d0 = dt * 32 + rr * 8 + hi * 4;
                float4 w;
                w.x = O[dt][rr * 4 + 0] * inv;
                w.y = O[dt][rr * 4 + 1] * inv;
                w.z = O[dt][rr * 4 + 2] * inv;
                w.w = O[dt][rr * 4 + 3] * inv;
                *(float4*)(op + d0) = w;
            }
    } else {
        _Float16* op = O2ws + ((size_t)b * kL + q) * kD;
#pragma unroll
        for (int dt = 0; dt < 2; ++dt)
#pragma unroll
            for (int rr = 0; rr < 4; ++rr) {
                const int d0 = dt * 32 + rr * 8 + hi * 4;
                half4_t w = cvt_pk4(O[dt][rr * 4 + 0] * inv, O[dt][rr * 4 + 1] * inv,
                                    O[dt][rr * 4 + 2] * inv, O[dt][rr * 4 + 3] * inv);
                *(half4_t*)(op + d0) = w;
            }
    }
    if (hi == 0) {
        float* mp = Mlws + (((size_t)b * kL + q) * 2 + hf) * 2;
        mp[0] = m_run;
        mp[1] = l_run;
    }
}

// Merge the two key-halves: Out = w1*O1 + w2*O2, w_i = l_i*2^(m_i-m) / sum.
__global__ __launch_bounds__(256)
void combine(float* __restrict__ Out, const _Float16* __restrict__ O2ws,
             const float* __restrict__ Mlws)
{
    const int t   = threadIdx.x;
    const int row = blockIdx.x * 16 + (t >> 4);   // global row in [0, kB*kL)
    const int d0  = (t & 15) * 4;

    const float m1 = Mlws[(size_t)row * 4 + 0];
    const float l1 = Mlws[(size_t)row * 4 + 1];
    const float m2 = Mlws[(size_t)row * 4 + 2];
    const float l2 = Mlws[(size_t)row * 4 + 3];

    const float m  = fmaxf(m1, m2);
    float w1 = l1 * exp2f(m1 - m);
    float w2 = l2 * exp2f(m2 - m);
    const float inv = 1.0f / (w1 + w2);
    w1 *= inv; w2 *= inv;

    float* op = Out + (size_t)row * kD + d0;
    const _Float16* o2 = O2ws + (size_t)row * kD + d0;
    float4 a = *(const float4*)op;
    const half4_t h = *(const half4_t*)o2;
    a.x = a.x * w1 + (float)h[0] * w2;
    a.y = a.y * w1 + (float)h[1] * w2;
    a.z = a.z * w1 + (float)h[2] * w2;
    a.w = a.w * w1 + (float)h[3] * w2;
    *(float4*)op = a;
}

extern "C" void kernel_launch(void* const* d_in, const int* in_sizes, int n_in,
                              void* d_out, int out_size, void* d_ws, size_t ws_size,
                              hipStream_t stream) {
    const float* Q = (const float*)d_in[0];
    const float* K = (const float*)d_in[1];
    const float* V = (const float*)d_in[2];
    const float* s = (const float*)d_in[3];
    float* out = (float*)d_out;
    _Float16* Kws  = (_Float16*)d_ws;
    _Float16* Vws  = Kws + kWsHalves;
    _Float16* O2ws = Vws + kWsHalves;                 // 8.4 MB fp16 partial (half 1)
    float*    Mlws = (float*)(O2ws + kOHalves);       // [b*L][half][{m,l}] = 1.05 MB
    // total ws use: 16.8 + 8.4 + 1.05 = 26.2 MB  (>=34 MB proven in R5)

    prep_kv<<<dim3(2 * kB * kTiles), dim3(256), 0, stream>>>(K, V, Kws, Vws);
    fa_fwd<<<dim3(kL / kQTile, kB, kSplit), dim3(256), 0, stream>>>(Q, Kws, Vws, s, out, O2ws, Mlws);
    combine<<<dim3(kB * kL / 16), dim3(256), 0, stream>>>(out, O2ws, Mlws);
}

// Round 3
// 186.008 us; speedup vs baseline: 1.0860x; 1.0134x over previous
//
#include <hip/hip_runtime.h>
#include <hip/hip_fp16.h>

typedef _Float16 half2_t __attribute__((ext_vector_type(2)));
typedef _Float16 half4_t __attribute__((ext_vector_type(4)));
typedef _Float16 half8_t __attribute__((ext_vector_type(8)));
typedef float   float4_t __attribute__((ext_vector_type(4)));
typedef float  float16_t __attribute__((ext_vector_type(16)));

static __device__ __forceinline__ half2_t cvt_pk(float a, float b) {
    return __builtin_bit_cast(half2_t, __builtin_amdgcn_cvt_pkrtz(a, b));
}
static __device__ __forceinline__ half4_t cvt_pk4(float a, float b, float c, float d) {
    half2_t lo = cvt_pk(a, b), hi = cvt_pk(c, d);
    half4_t r;
    r[0] = lo[0]; r[1] = lo[1]; r[2] = hi[0]; r[3] = hi[1];
    return r;
}
static __device__ __forceinline__ half8_t cvt_pk8(const float4& a, const float4& b) {
    half4_t lo = cvt_pk4(a.x, a.y, a.z, a.w);
    half4_t hi = cvt_pk4(b.x, b.y, b.z, b.w);
    return __builtin_shufflevector(lo, hi, 0, 1, 2, 3, 4, 5, 6, 7);
}
static __device__ __forceinline__ half8_t join8(half4_t lo, half4_t hi) {
    return __builtin_shufflevector(lo, hi, 0, 1, 2, 3, 4, 5, 6, 7);
}
static __device__ __forceinline__ float f3(float a, float b, float c) {
    return fmaxf(fmaxf(a, b), c);   // clang fuses to v_max3_f32 (T17)
}

namespace {
constexpr int kB       = 16;    // batch
constexpr int kL       = 4096;  // Lq == Lk
constexpr int kD       = 64;    // head dim
constexpr int kQTile   = 128;   // 4 waves x 32 q-rows
constexpr int kBK      = 64;    // keys per tile
constexpr int kTiles   = kL / kBK;          // 64 key-tiles per batch
constexpr int kSplit   = 2;                 // K-split (grid 1024)
constexpr int kTilesHf = kTiles / kSplit;   // 32 key-tiles per half
constexpr int kTileH   = kBK * kD;          // 4096 halves per tile image
constexpr int kKStride = 72;    // Ksh stride (halves): b128 reads, even bank groups
constexpr int kVStride = 72;    // Vsh stride (halves): b128 reads/writes
constexpr size_t kWsHalves = (size_t)kB * kTiles * kTileH;  // 8 MB per operand
constexpr size_t kOHalves  = (size_t)kB * kL * kD;          // 8 MB fp16 partial O
}

// v14: latency attack on v13 (101.7us, no pipe >50% -> dependency-bound).
//  - single-barrier double-buffered LDS: compute buf[cur] starts right after
//    the barrier; commits of tile t+1 go to buf[cur^1] concurrently. The old
//    {barrier; commit; barrier; compute} serialization is gone.
//  - l pair-combine (shfl_xor 32) deferred to epilogue: both lane-halves share
//    the same m history (max shfl keeps m pair-uniform), so l is additive.
//  - max tree via v_max3 triples (31 -> ~17 ops, shorter dep chain).
//  - s_setprio(1) around QK/PV MFMA clusters (T5, attn-positive regime).
//  - launch_bounds(256,4): VGPR<=128 so 4 blocks/CU stay legal at 36.9KB LDS.
// Math identical to v13: 32x32x16 QK/PV, key-bit-swap K image, defer-max THR=8.

__global__ __launch_bounds__(256) void prep_kv(const float* __restrict__ K,
                                               const float* __restrict__ V,
                                               _Float16* __restrict__ Kws,
                                               _Float16* __restrict__ Vws)
{
    int blk = blockIdx.x;
    const int tid = threadIdx.x;
    if (blk < kB * kTiles) {
        // K image: fp16 row-major per tile, with key bits 2<->3 swapped so the
        // 32x32 MFMA S-reg order matches the PV B-operand key order.
        const float* src = K + (size_t)blk * kTileH;
        _Float16* dst = Kws + (size_t)blk * kTileH;
#pragma unroll
        for (int i = 0; i < 2; ++i) {
            const int task = tid + 256 * i;
            const int row  = task >> 3;       // dst physical row 0..63
            const int g    = task & 7;
            const int srow = (row & ~12) | ((row & 4) << 1) | ((row & 8) >> 1);
            const float* p = src + srow * kD + g * 8;
            const float4 a  = *(const float4*)p;
            const float4 b2 = *(const float4*)(p + 4);
            *(half8_t*)(dst + task * 8) = cvt_pk8(a, b2);
        }
    } else {
        // V^T image: [c8 chunk][d][8 keys] halves; natural key order
        blk -= kB * kTiles;
        const float* src = V + (size_t)blk * kTileH;   // [key][d]
        _Float16* dst = Vws + (size_t)blk * kTileH;
        const int d  = tid & 63;
        const int vw = tid >> 6;
#pragma unroll
        for (int i = 0; i < 2; ++i) {
            const int c8 = vw * 2 + i;
            const int k0 = c8 * 8;
            float p[8];
#pragma unroll
            for (int j = 0; j < 8; ++j) p[j] = src[(k0 + j) * kD + d];
            half4_t lo = cvt_pk4(p[0], p[1], p[2], p[3]);
            half4_t hi = cvt_pk4(p[4], p[5], p[6], p[7]);
            *(half8_t*)(dst + (c8 * 64 + d) * 8) = join8(lo, hi);
        }
    }
}

__global__ __launch_bounds__(256, 4)
void fa_fwd(const float* __restrict__ Q, const _Float16* __restrict__ Kws,
            const _Float16* __restrict__ Vws, const float* __restrict__ scale_ptr,
            float* __restrict__ Out, _Float16* __restrict__ O2ws,
            float* __restrict__ Mlws)
{
    __shared__ __align__(16) _Float16 Ksh[2][kBK * kKStride];  // [buf][key_phys][d]
    __shared__ __align__(16) _Float16 Vsh[2][kD * kVStride];   // [buf][d][key] (V^T)

    const int tid  = threadIdx.x;
    const int wave = tid >> 6;
    const int lane = tid & 63;
    const int l31  = lane & 31;   // q-row (QK B / PV B col); key row (QK A); d row (PV A)
    const int hi   = lane >> 5;   // half-select: k = hi*8 + j

    const int b  = blockIdx.y;
    const int hf = blockIdx.z;    // key-split half
    const int q0 = blockIdx.x * kQTile + wave * 32;

    // staging decompositions (match image layouts)
    const int task0 = tid, task1 = tid + 256;          // K: row=task>>3, g=task&7
    const int vd = tid & 63;                           // V: this thread's d
    const int vw = tid >> 6;                           // V: chunk pair base
    const int koff0 = (task0 >> 3) * kKStride + (task0 & 7) * 8;
    const int koff1 = (task1 >> 3) * kKStride + (task1 & 7) * 8;
    const int voff0 = vd * kVStride + (vw * 2 + 0) * 8;
    const int voff1 = vd * kVStride + (vw * 2 + 1) * 8;

    const float qscale = 1.4426950408889634f / scale_ptr[0];

    const float*    Qb = Q   + (size_t)b * kL * kD;
    const _Float16* Kt = Kws + ((size_t)b * kTiles + (size_t)hf * kTilesHf) * kTileH;
    const _Float16* Vt = Vws + ((size_t)b * kTiles + (size_t)hf * kTilesHf) * kTileH;

    // ---- Q fragments (B-operand 32x32x16: n=l31=qrow, k=hi*8+j, d=kd*16+k) ----
    half8_t qfrag[4];
    {
        const float* qrow = Qb + (size_t)(q0 + l31) * kD;
#pragma unroll
        for (int kd = 0; kd < 4; ++kd) {
            const float* p = qrow + kd * 16 + hi * 8;
            half8_t h;
#pragma unroll
            for (int j = 0; j < 8; ++j) h[j] = (_Float16)(p[j] * qscale);
            qfrag[kd] = h;
        }
    }

    // O^T accumulators: col=l31=q, row=d=(r&3)+8*(r>>2)+4*hi (+32*dt)
    float16_t O[2];
    O[0] = (float16_t)0.0f;
    O[1] = (float16_t)0.0f;
    float m_run = -__builtin_inff();
    float l_run = 0.0f;   // lane-local (this half's keys); pair-combined in epilogue
    const float16_t Zc = (float16_t)0.0f;

    // ---- prologue: stage tile 0 into buf0, prefetch tile 1 into regs ----
    half8_t kp[2], vp[2];
    kp[0] = *(const half8_t*)(Kt + task0 * 8);
    kp[1] = *(const half8_t*)(Kt + task1 * 8);
    vp[0] = *(const half8_t*)(Vt + ((vw * 2 + 0) * 64 + vd) * 8);
    vp[1] = *(const half8_t*)(Vt + ((vw * 2 + 1) * 64 + vd) * 8);
    *(half8_t*)(&Ksh[0][koff0]) = kp[0];
    *(half8_t*)(&Ksh[0][koff1]) = kp[1];
    *(half8_t*)(&Vsh[0][voff0]) = vp[0];
    *(half8_t*)(&Vsh[0][voff1]) = vp[1];
    {
        const _Float16* kn = Kt + (size_t)1 * kTileH;
        const _Float16* vn = Vt + (size_t)1 * kTileH;
        kp[0] = *(const half8_t*)(kn + task0 * 8);
        kp[1] = *(const half8_t*)(kn + task1 * 8);
        vp[0] = *(const half8_t*)(vn + ((vw * 2 + 0) * 64 + vd) * 8);
        vp[1] = *(const half8_t*)(vn + ((vw * 2 + 1) * 64 + vd) * 8);
    }
    __syncthreads();

    for (int t = 0; t < kTilesHf; ++t) {
        const int cur = t & 1;
        const _Float16* Kb = Ksh[cur];
        const _Float16* Vb = Vsh[cur];
        _Float16* Kn = Ksh[cur ^ 1];
        _Float16* Vn = Vsh[cur ^ 1];

        // ---- commit tile t+1 into the other buffer (overlaps with compute) ----
        *(half8_t*)(&Kn[koff0]) = kp[0];
        *(half8_t*)(&Kn[koff1]) = kp[1];
        *(half8_t*)(&Vn[voff0]) = vp[0];
        *(half8_t*)(&Vn[voff1]) = vp[1];

        // ---- issue global prefetch of tile t+2 (wraps; wrapped data unused) ----
        {
            const int nt = (t + 2) & (kTilesHf - 1);
            const _Float16* kn = Kt + (size_t)nt * kTileH;
            const _Float16* vn = Vt + (size_t)nt * kTileH;
            kp[0] = *(const half8_t*)(kn + task0 * 8);
            kp[1] = *(const half8_t*)(kn + task1 * 8);
            vp[0] = *(const half8_t*)(vn + ((vw * 2 + 0) * 64 + vd) * 8);
            vp[1] = *(const half8_t*)(vn + ((vw * 2 + 1) * 64 + vd) * 8);
        }

        // ---- S^T = K_phys * Q^T : 2 key-blocks x 4 d-chunks of 32x32x16 ----
        float16_t S0, S1;
        {
            half8_t kf0, kf1;
            kf0 = *(const half8_t*)(&Kb[(l31)      * kKStride + 0 * 16 + hi * 8]);
            kf1 = *(const half8_t*)(&Kb[(32 + l31) * kKStride + 0 * 16 + hi * 8]);
            __builtin_amdgcn_s_setprio(1);
            S0 = __builtin_amdgcn_mfma_f32_32x32x16_f16(kf0, qfrag[0], Zc, 0, 0, 0);
            S1 = __builtin_amdgcn_mfma_f32_32x32x16_f16(kf1, qfrag[0], Zc, 0, 0, 0);
#pragma unroll
            for (int kd = 1; kd < 4; ++kd) {
                kf0 = *(const half8_t*)(&Kb[(l31)      * kKStride + kd * 16 + hi * 8]);
                kf1 = *(const half8_t*)(&Kb[(32 + l31) * kKStride + kd * 16 + hi * 8]);
                S0 = __builtin_amdgcn_mfma_f32_32x32x16_f16(kf0, qfrag[kd], S0, 0, 0, 0);
                S1 = __builtin_amdgcn_mfma_f32_32x32x16_f16(kf1, qfrag[kd], S1, 0, 0, 0);
            }
            __builtin_amdgcn_s_setprio(0);
        }

        // ---- online softmax: max3 tree, ONE shfl_xor(32), lane-local l ----
        float v0 = f3(S0[0],  S0[1],  S0[2]);
        float v1 = f3(S0[3],  S0[4],  S0[5]);
        float v2 = f3(S0[6],  S0[7],  S0[8]);
        float v3 = f3(S0[9],  S0[10], S0[11]);
        float v4 = f3(S0[12], S0[13], S0[14]);
        float v5 = f3(S0[15], S1[0],  S1[1]);
        float v6 = f3(S1[2],  S1[3],  S1[4]);
        float v7 = f3(S1[5],  S1[6],  S1[7]);
        float v8 = f3(S1[8],  S1[9],  S1[10]);
        float v9 = f3(S1[11], S1[12], S1[13]);
        float w0 = f3(v0, v1, v2);
        float w1 = f3(v3, v4, v5);
        float w2 = f3(v6, v7, v8);
        float w3 = f3(v9, S1[14], S1[15]);
        float pm = fmaxf(fmaxf(w0, w1), fmaxf(w2, w3));
        pm = fmaxf(pm, __shfl_xor(pm, 32));

        // T13 defer-max: skip rescale while growth <= 8 (P bounded by 2^8, exact)
        const bool need = pm > m_run + 8.0f;
        if (__ballot(need)) {
            const float mn    = fmaxf(m_run, pm);
            const float alpha = __builtin_amdgcn_exp2f(m_run - mn);  // 1st iter: 0
            m_run = mn;
            l_run *= alpha;
#pragma unroll
            for (int r = 0; r < 16; ++r) { O[0][r] *= alpha; O[1][r] *= alpha; }
        }

        // ---- P = exp2(S - m) in place; pack B-fragments; local l sum ----
#pragma unroll
        for (int r = 0; r < 16; ++r) {
            S0[r] = __builtin_amdgcn_exp2f(S0[r] - m_run);
            S1[r] = __builtin_amdgcn_exp2f(S1[r] - m_run);
        }
        half8_t pf[4];
        pf[0] = join8(cvt_pk4(S0[0],  S0[1],  S0[2],  S0[3]),
                      cvt_pk4(S0[4],  S0[5],  S0[6],  S0[7]));
        pf[1] = join8(cvt_pk4(S0[8],  S0[9],  S0[10], S0[11]),
                      cvt_pk4(S0[12], S0[13], S0[14], S0[15]));
        pf[2] = join8(cvt_pk4(S1[0],  S1[1],  S1[2],  S1[3]),
                      cvt_pk4(S1[4],  S1[5],  S1[6],  S1[7]));
        pf[3] = join8(cvt_pk4(S1[8],  S1[9],  S1[10], S1[11]),
                      cvt_pk4(S1[12], S1[13], S1[14], S1[15]));
#define A4(v,a) ((v[a] + v[(a)+1]) + (v[(a)+2] + v[(a)+3]))
        l_run += ((A4(S0, 0) + A4(S0, 4)) + (A4(S0, 8) + A4(S0, 12)))
               + ((A4(S1, 0) + A4(S1, 4)) + (A4(S1, 8) + A4(S1, 12)));
#undef A4

        // ---- O^T += V^T * P : 4 key16-blocks x 2 d-blocks, full-rate x32x16 ----
        __builtin_amdgcn_s_setprio(1);
#pragma unroll
        for (int kb = 0; kb < 4; ++kb) {
            const half8_t vf0 = *(const half8_t*)(
                &Vb[(l31)      * kVStride + kb * 16 + hi * 8]);
            const half8_t vf1 = *(const half8_t*)(
                &Vb[(32 + l31) * kVStride + kb * 16 + hi * 8]);
            O[0] = __builtin_amdgcn_mfma_f32_32x32x16_f16(vf0, pf[kb], O[0], 0, 0, 0);
            O[1] = __builtin_amdgcn_mfma_f32_32x32x16_f16(vf1, pf[kb], O[1], 0, 0, 0);
        }
        __builtin_amdgcn_s_setprio(0);

        // single barrier per tile: reads of buf[cur] done; writes to buf[cur^1] done
        __syncthreads();
    }

    // ---- epilogue: combine lane-pair l; O^T reg r -> d=(r&3)+8*(r>>2)+4*hi+32*dt ----
    l_run += __shfl_xor(l_run, 32);
    const float inv = 1.0f / l_run;
    const int   q   = q0 + l31;
    if (hf == 0) {
        float* op = Out + ((size_t)b * kL + q) * kD;
#pragma unroll
        for (int dt = 0; dt < 2; ++dt)
#pragma unroll
            for (int rr = 0; rr < 4; ++rr) {
                const int d0 = dt * 32 + rr * 8 + hi * 4;
                float4 w;
                w.x = O[dt][rr * 4 + 0] * inv;
                w.y = O[dt][rr * 4 + 1] * inv;
                w.z = O[dt][rr * 4 + 2] * inv;
                w.w = O[dt][rr * 4 + 3] * inv;
                *(float4*)(op + d0) = w;
            }
    } else {
        _Float16* op = O2ws + ((size_t)b * kL + q) * kD;
#pragma unroll
        for (int dt = 0; dt < 2; ++dt)
#pragma unroll
            for (int rr = 0; rr < 4; ++rr) {
                const int d0 = dt * 32 + rr * 8 + hi * 4;
                half4_t w = cvt_pk4(O[dt][rr * 4 + 0] * inv, O[dt][rr * 4 + 1] * inv,
                                    O[dt][rr * 4 + 2] * inv, O[dt][rr * 4 + 3] * inv);
                *(half4_t*)(op + d0) = w;
            }
    }
    if (hi == 0) {
        float2 ml; ml.x = m_run; ml.y = l_run;
        *(float2*)(Mlws + (((size_t)b * kL + q) * 2 + hf) * 2) = ml;
    }
}

// Merge the two key-halves: Out = w1*O1 + w2*O2, w_i = l_i*2^(m_i-m) / sum.
__global__ __launch_bounds__(256)
void combine(float* __restrict__ Out, const _Float16* __restrict__ O2ws,
             const float* __restrict__ Mlws)
{
    const int t   = threadIdx.x;
    const int row = blockIdx.x * 16 + (t >> 4);   // global row in [0, kB*kL)
    const int d0  = (t & 15) * 4;

    const float m1 = Mlws[(size_t)row * 4 + 0];
    const float l1 = Mlws[(size_t)row * 4 + 1];
    const float m2 = Mlws[(size_t)row * 4 + 2];
    const float l2 = Mlws[(size_t)row * 4 + 3];

    const float m  = fmaxf(m1, m2);
    float w1 = l1 * exp2f(m1 - m);
    float w2 = l2 * exp2f(m2 - m);
    const float inv = 1.0f / (w1 + w2);
    w1 *= inv; w2 *= inv;

    float* op = Out + (size_t)row * kD + d0;
    const _Float16* o2 = O2ws + (size_t)row * kD + d0;
    float4 a = *(const float4*)op;
    const half4_t h = *(const half4_t*)o2;
    a.x = a.x * w1 + (float)h[0] * w2;
    a.y = a.y * w1 + (float)h[1] * w2;
    a.z = a.z * w1 + (float)h[2] * w2;
    a.w = a.w * w1 + (float)h[3] * w2;
    *(float4*)op = a;
}

extern "C" void kernel_launch(void* const* d_in, const int* in_sizes, int n_in,
                              void* d_out, int out_size, void* d_ws, size_t ws_size,
                              hipStream_t stream) {
    const float* Q = (const float*)d_in[0];
    const float* K = (const float*)d_in[1];
    const float* V = (const float*)d_in[2];
    const float* s = (const float*)d_in[3];
    float* out = (float*)d_out;
    _Float16* Kws  = (_Float16*)d_ws;
    _Float16* Vws  = Kws + kWsHalves;
    _Float16* O2ws = Vws + kWsHalves;                 // 8.4 MB fp16 partial (half 1)
    float*    Mlws = (float*)(O2ws + kOHalves);       // [b*L][half][{m,l}] = 1.05 MB
    // total ws use: 16.8 + 8.4 + 1.05 = 26.2 MB  (>=34 MB proven in R5)

    prep_kv<<<dim3(2 * kB * kTiles), dim3(256), 0, stream>>>(K, V, Kws, Vws);
    fa_fwd<<<dim3(kL / kQTile, kB, kSplit), dim3(256), 0, stream>>>(Q, Kws, Vws, s, out, O2ws, Mlws);
    combine<<<dim3(kB * kL / 16), dim3(256), 0, stream>>>(out, O2ws, Mlws);
}